// Round 7
// baseline (1465.455 us; speedup 1.0000x reference)
//
#include <hip/hip_runtime.h>
#include <hip/hip_bf16.h>
#include <math.h>

// DeepGESN: 2 layers of h = tanh(wiu + L @ (h @ W_hh^T)), 10 iters each.
// Rewrite: L@(h@W) == (L@h)@W. G=L@h in bf16 MFMA with two-term split
// (L=Lhi+Llo, h=hhi+hlo, 3 products; measured absmax 0.0093 vs 0.02 thr).
//
// R7: PERSISTENT single-dispatch kernel. 256 blocks x 512 thr, 1 block/CU
// (forced by 128KB LDS). Each wave holds its 32KB A-slice in 128 VGPRs for
// the WHOLE run (A read once, not 18x). Hand-rolled device-scope grid
// barrier replaces the 38 kernel boundaries. mm/post/input phases are the
// verified R6 code as device functions sharing one smem arena.
//
// Pack layouts (lane-linear dwordx4 fragment loads):
//  Apack[rb][kb][l][8]: val = L[rb*16 + (l&15)][kb*32 + 8*(l>>4) + j]
//  Bpack[kb][cf][l][8]: val = h[kb*32 + 8*(l>>4) + j][cf*16 + (l&15)]
// mfma_f32_16x16x32_bf16: D[(l>>4)*4+r][l&15] (m89/m91 layout).

#define NN 4096
#define HH 64
#define NBLK 256
#define TPB 512

typedef float  f32x4  __attribute__((ext_vector_type(4)));
typedef short  bf16x8 __attribute__((ext_vector_type(8)));

static __device__ __forceinline__ unsigned short bf16_bits(__hip_bfloat16 b) {
    union { __hip_bfloat16 b; unsigned short u; } cv; cv.b = b; return cv.u;
}

// ---------------------------------------------------------------------------
// Split + pack L -> Ahi/Alo (bf16 fragment-linear, 32MB each)
// grid 8192: rb = bid>>5 (256), kg = bid&31 (128-k group)
// ---------------------------------------------------------------------------
__global__ __launch_bounds__(256) void convert_L(
    const float* __restrict__ L, short* __restrict__ Ahi, short* __restrict__ Alo)
{
    __shared__ float T[16 * 132];
    const int t  = threadIdx.x;
    const int rb = blockIdx.x >> 5;
    const int kg = blockIdx.x & 31;

    {
        const int row = t >> 4;
        const int c4  = (t & 15) * 4;
        const float* src = L + (size_t)(rb * 16 + row) * NN + kg * 128;
        float4 v0 = *reinterpret_cast<const float4*>(src + c4);
        float4 v1 = *reinterpret_cast<const float4*>(src + c4 + 64);
        *reinterpret_cast<float4*>(&T[row * 132 + c4])      = v0;
        *reinterpret_cast<float4*>(&T[row * 132 + c4 + 64]) = v1;
    }
    __syncthreads();

    const int kbl = t >> 6;
    const int l   = t & 63;
    const int r   = l & 15, g = l >> 4;
    short hi8[8], lo8[8];
#pragma unroll
    for (int j = 0; j < 8; ++j) {
        const float v = T[r * 132 + kbl * 32 + g * 8 + j];
        __hip_bfloat16 bh = __float2bfloat16(v);
        const float vh = __bfloat162float(bh);
        __hip_bfloat16 bl = __float2bfloat16(v - vh);
        hi8[j] = (short)bf16_bits(bh);
        lo8[j] = (short)bf16_bits(bl);
    }
    const size_t off = ((size_t)(rb * 128 + kg * 4 + kbl) * 64 + l) * 8;
    *reinterpret_cast<bf16x8*>(Ahi + off) = *reinterpret_cast<bf16x8*>(hi8);
    *reinterpret_cast<bf16x8*>(Alo + off) = *reinterpret_cast<bf16x8*>(lo8);
}

// ---------------------------------------------------------------------------
// Device-scope grid barrier (sense-reversing). All NBLK blocks co-resident
// by construction (128KB LDS -> 1 block/CU, NBLK == CU count).
// ---------------------------------------------------------------------------
__device__ __forceinline__ void grid_barrier(unsigned* cnt, unsigned* gen, int nb)
{
    __syncthreads();
    if (threadIdx.x == 0) {
        __threadfence();                                     // release our writes
        unsigned g = __hip_atomic_load(gen, __ATOMIC_RELAXED,
                                       __HIP_MEMORY_SCOPE_AGENT);
        unsigned old = __hip_atomic_fetch_add(cnt, 1u, __ATOMIC_ACQ_REL,
                                              __HIP_MEMORY_SCOPE_AGENT);
        if (old == (unsigned)(nb - 1)) {
            __hip_atomic_store(cnt, 0u, __ATOMIC_RELAXED,
                               __HIP_MEMORY_SCOPE_AGENT);
            __hip_atomic_fetch_add(gen, 1u, __ATOMIC_RELEASE,
                                   __HIP_MEMORY_SCOPE_AGENT);
        } else {
            while (__hip_atomic_load(gen, __ATOMIC_ACQUIRE,
                                     __HIP_MEMORY_SCOPE_AGENT) == g) {
                __builtin_amdgcn_s_sleep(2);
            }
        }
        __threadfence();                                     // acquire side
    }
    __syncthreads();
}

// ---------------------------------------------------------------------------
// Post phase (device fn, 512 thr): z = (wiu_in?) + (reduce_s Gsrc) @ W^T,
// h = tanh(z); writes hf32, B-pack, optional out2, optional wiu_out.
// nsplit==0: Gsrc is x [4096][64] directly (input phase, computes wiu).
// Block handles rows r0..r0+15. smem arena: W(16640) G(4352) Hi(2112) Lo(2112).
// ---------------------------------------------------------------------------
__device__ __forceinline__ void post_phase(
    const float* __restrict__ Gsrc, int nsplit,
    const float* __restrict__ wiu_in, float* __restrict__ wiu_out,
    const float* __restrict__ W, float* __restrict__ hf32,
    short* __restrict__ Bhi, short* __restrict__ Blo,
    float* __restrict__ out2, int outc0, int r0, char* smem)
{
    float* W_lds = (float*)smem;                              // 64*65 f32
    float* G_lds = (float*)(smem + 16640);                    // 16*68 f32
    unsigned short* Hi_lds = (unsigned short*)(smem + 16640 + 4352);   // 16*66
    unsigned short* Lo_lds = (unsigned short*)(smem + 16640 + 4352 + 2112);
    const int t = threadIdx.x;

    {   // W load: 512 thr x 8 elems
        const int j  = t >> 3;
        const int k0 = (t & 7) * 8;
#pragma unroll
        for (int q = 0; q < 8; ++q)
            W_lds[j * 65 + k0 + q] = W[j * 64 + k0 + q];
    }
    if (t < 256) {  // load(+reduce) G: 16x64 f32 = 256 float4
        const int row = t >> 4;
        const int c4  = (t & 15) * 4;
        float4 sum;
        if (nsplit == 0) {
            sum = *reinterpret_cast<const float4*>(
                Gsrc + (size_t)(r0 + row) * HH + c4);
        } else {
            sum = make_float4(0.f, 0.f, 0.f, 0.f);
            for (int sidx = 0; sidx < nsplit; ++sidx) {
                const float4 v = *reinterpret_cast<const float4*>(
                    Gsrc + (size_t)sidx * NN * HH + (size_t)(r0 + row) * HH + c4);
                sum.x += v.x; sum.y += v.y; sum.z += v.z; sum.w += v.w;
            }
        }
        *reinterpret_cast<float4*>(&G_lds[row * 68 + c4]) = sum;
    }
    __syncthreads();

    const int j  = t & 63;
    const int ig = t >> 6;              // 0..7, wave-uniform
#pragma unroll
    for (int rr = 0; rr < 2; ++rr) {
        const int i = ig * 2 + rr;      // 0..15
        float z = wiu_in ? wiu_in[(size_t)(r0 + i) * HH + j] : 0.f;
#pragma unroll
        for (int m = 0; m < 64; ++m)
            z = fmaf(G_lds[i * 68 + m], W_lds[j * 65 + m], z);
        if (wiu_out) wiu_out[(size_t)(r0 + i) * HH + j] = z;
        const float hv = tanhf(z);
        hf32[(size_t)(r0 + i) * HH + j] = hv;
        if (out2) out2[(size_t)(r0 + i) * 128 + outc0 + j] = hv;
        __hip_bfloat16 bh = __float2bfloat16(hv);
        const float vh = __bfloat162float(bh);
        __hip_bfloat16 bl = __float2bfloat16(hv - vh);
        Hi_lds[i * 66 + j] = bf16_bits(bh);
        Lo_lds[i * 66 + j] = bf16_bits(bl);
    }
    __syncthreads();

    // pack: 128 threads, each owns 8 consecutive rows at one column
    if (t < 128) {
        const int j2     = t & 63;
        const int glocal = t >> 6;                     // 0..1
        const int kb     = r0 >> 5;
        const int gg     = ((r0 & 31) >> 3) + glocal;  // 8-row group in kb
        const int cf     = j2 >> 4;
        const int lane   = gg * 16 + (j2 & 15);
        short hi8[8], lo8[8];
#pragma unroll
        for (int jj = 0; jj < 8; ++jj) {
            const int i = glocal * 8 + jj;
            hi8[jj] = (short)Hi_lds[i * 66 + j2];
            lo8[jj] = (short)Lo_lds[i * 66 + j2];
        }
        const size_t off = ((size_t)(kb * 4 + cf) * 64 + lane) * 8;
        *reinterpret_cast<bf16x8*>(Bhi + off) = *reinterpret_cast<bf16x8*>(hi8);
        *reinterpret_cast<bf16x8*>(Blo + off) = *reinterpret_cast<bf16x8*>(lo8);
    }
    // caller's grid_barrier starts with __syncthreads -> covers pack readers
}

// ---------------------------------------------------------------------------
// Persistent kernel: whole 2-layer x 10-iter recurrence in one dispatch.
// block b: mm role (p = b>>3 row-panel, s = b&7 K-split), post role rows b*16.
// ---------------------------------------------------------------------------
__global__ __launch_bounds__(TPB, 2) void gesn_persistent(
    const short* __restrict__ Ahi, const short* __restrict__ Alo,
    short* __restrict__ Bhi, short* __restrict__ Blo,
    const float* __restrict__ X,
    const float* __restrict__ Wih0, const float* __restrict__ Whh0,
    const float* __restrict__ Wih1, const float* __restrict__ Whh1,
    float* __restrict__ wiu, float* __restrict__ hA, float* __restrict__ hB,
    float* __restrict__ Gp, float* __restrict__ out,
    unsigned* bar_cnt, unsigned* bar_gen)
{
    __shared__ char smem[131072];      // 128KB arena -> 1 block/CU
    const int t = threadIdx.x;
    const int b = blockIdx.x;
    const int w = t >> 6, l = t & 63;
    const int p = b >> 3, s = b & 7;
    const int rb  = p * 8 + w;         // this wave's 16-row block
    const int kb0 = s * 16;
    const int r0  = b * 16;            // post-role rows

    // A-slice resident in VGPRs for the entire run (32 loads, 128 VGPRs)
    const size_t abase = ((size_t)(rb * 128 + kb0) * 64 + l) * 8;
    bf16x8 aH[16], aL[16];
#pragma unroll
    for (int q = 0; q < 16; ++q) {
        aH[q] = *reinterpret_cast<const bf16x8*>(Ahi + abase + (size_t)q * 512);
        aL[q] = *reinterpret_cast<const bf16x8*>(Alo + abase + (size_t)q * 512);
    }

    for (int layer = 0; layer < 2; ++layer) {
        const float* x   = layer ? hA : X;
        const float* Wih = layer ? Wih1 : Wih0;
        const float* Whh = layer ? Whh1 : Whh0;
        float* hcur      = layer ? hB : hA;

        // iter 1: wiu = x@Wih^T; h = tanh(wiu); pack B
        post_phase(x, 0, nullptr, wiu, Wih, hcur, Bhi, Blo, nullptr, 0, r0, smem);
        grid_barrier(bar_cnt, bar_gen, NBLK);

        for (int it = 0; it < 9; ++it) {
            // ---- mm phase: Gp[s] = partial (L @ h) over K-split s ----
            short* Bh_lds = (short*)smem;            // 64KB [kbl][cf][l][8]
            short* Bl_lds = (short*)(smem + 65536);  // 64KB
            {
                const short* srcH = Bhi + (size_t)kb0 * 4 * 64 * 8;
                const short* srcL = Blo + (size_t)kb0 * 4 * 64 * 8;
#pragma unroll
                for (int q = 0; q < 8; ++q) {
                    const int idx = (q * 512 + t) * 8;
                    *reinterpret_cast<bf16x8*>(&Bh_lds[idx]) =
                        *reinterpret_cast<const bf16x8*>(srcH + idx);
                    *reinterpret_cast<bf16x8*>(&Bl_lds[idx]) =
                        *reinterpret_cast<const bf16x8*>(srcL + idx);
                }
            }
            __syncthreads();

            f32x4 accP[4] = {};        // aH*bH
            f32x4 accQ[4] = {};        // aH*bL + aL*bH
#pragma unroll
            for (int kbl = 0; kbl < 16; ++kbl) {
                bf16x8 bH[4], bL[4];
#pragma unroll
                for (int cf = 0; cf < 4; ++cf) {
                    const int idx = ((kbl * 4 + cf) * 64 + l) * 8;
                    bH[cf] = *reinterpret_cast<const bf16x8*>(&Bh_lds[idx]);
                    bL[cf] = *reinterpret_cast<const bf16x8*>(&Bl_lds[idx]);
                }
#pragma unroll
                for (int cf = 0; cf < 4; ++cf) {
                    accP[cf] = __builtin_amdgcn_mfma_f32_16x16x32_bf16(
                        aH[kbl], bH[cf], accP[cf], 0, 0, 0);
                    accQ[cf] = __builtin_amdgcn_mfma_f32_16x16x32_bf16(
                        aH[kbl], bL[cf], accQ[cf], 0, 0, 0);
                    accQ[cf] = __builtin_amdgcn_mfma_f32_16x16x32_bf16(
                        aL[kbl], bH[cf], accQ[cf], 0, 0, 0);
                }
            }
            {
                float* g = Gp + (size_t)s * NN * HH;
                const int col0  = l & 15;
                const int rbase = (l >> 4) * 4;
#pragma unroll
                for (int cf = 0; cf < 4; ++cf)
#pragma unroll
                    for (int r = 0; r < 4; ++r)
                        g[(size_t)(rb * 16 + rbase + r) * HH + cf * 16 + col0]
                            = accP[cf][r] + accQ[cf][r];
            }
            grid_barrier(bar_cnt, bar_gen, NBLK);    // Gp ready

            float* o2 = (it == 8) ? out : nullptr;
            post_phase(Gp, 8, wiu, nullptr, Whh, hcur, Bhi, Blo,
                       o2, layer * 64, r0, smem);
            grid_barrier(bar_cnt, bar_gen, NBLK);    // h/B-pack ready
        }
    }
}

// ---------------------------------------------------------------------------
// Fallback f32 path (round-0 kernels, small-ws safety)
// ---------------------------------------------------------------------------
__global__ __launch_bounds__(256) void gesn_input_kernel(
    const float* __restrict__ x, const float* __restrict__ W,
    float* __restrict__ wiu, float* __restrict__ h)
{
    __shared__ float W_lds[64 * 65];
    __shared__ float x_lds[256];
    const int t = threadIdx.x;
    {
        const int j  = t >> 2;
        const int k0 = (t & 3) << 4;
#pragma unroll
        for (int q = 0; q < 16; ++q)
            W_lds[j * 65 + k0 + q] = W[j * 64 + k0 + q];
    }
    const int i0 = blockIdx.x * 4;
    x_lds[t] = x[i0 * 64 + t];
    __syncthreads();
    const int j = t & 63, i = t >> 6;
    float z = 0.f;
#pragma unroll
    for (int k = 0; k < 64; ++k)
        z = fmaf(x_lds[i * 64 + k], W_lds[j * 65 + k], z);
    const int gidx = (i0 + i) * 64 + j;
    wiu[gidx] = z;
    h[gidx]   = tanhf(z);
}

__global__ __launch_bounds__(256) void gesn_iter_kernel(
    const float* __restrict__ L, const float* __restrict__ h_in,
    const float* __restrict__ wiu, const float* __restrict__ W,
    float* __restrict__ h_out, float* __restrict__ out2, int out_col0)
{
    __shared__ float h_lds[64 * 64];
    __shared__ float L_lds[16 * 68];
    __shared__ float G_lds[16 * 68];
    __shared__ float W_lds[64 * 65];
    const int t = threadIdx.x;
    {
        const int j  = t >> 2;
        const int k0 = (t & 3) << 4;
#pragma unroll
        for (int q = 0; q < 16; ++q)
            W_lds[j * 65 + k0 + q] = W[j * 64 + k0 + q];
    }
    const int r0 = blockIdx.x * 16;
    const int p  = t >> 5;
    const int c0 = (t & 31) * 2;
    float acc00 = 0.f, acc01 = 0.f, acc10 = 0.f, acc11 = 0.f;
    const int lr = t >> 4;
    const int lc = (t & 15) * 4;
    for (int kb = 0; kb < 64; ++kb) {
        __syncthreads();
        const float4 lv = *reinterpret_cast<const float4*>(
            &L[(size_t)(r0 + lr) * 4096 + kb * 64 + lc]);
        *reinterpret_cast<float4*>(&L_lds[lr * 68 + lc]) = lv;
        const float4* hsrc = reinterpret_cast<const float4*>(h_in + kb * 4096);
        float4* hdst = reinterpret_cast<float4*>(h_lds);
#pragma unroll
        for (int q = 0; q < 4; ++q)
            hdst[t + 256 * q] = hsrc[t + 256 * q];
        __syncthreads();
#pragma unroll
        for (int kk = 0; kk < 64; ++kk) {
            const float  lv0 = L_lds[(2 * p) * 68 + kk];
            const float  lv1 = L_lds[(2 * p + 1) * 68 + kk];
            const float2 hv  = *reinterpret_cast<const float2*>(&h_lds[kk * 64 + c0]);
            acc00 = fmaf(lv0, hv.x, acc00);
            acc01 = fmaf(lv0, hv.y, acc01);
            acc10 = fmaf(lv1, hv.x, acc10);
            acc11 = fmaf(lv1, hv.y, acc11);
        }
    }
    G_lds[(2 * p) * 68 + c0]         = acc00;
    G_lds[(2 * p) * 68 + c0 + 1]     = acc01;
    G_lds[(2 * p + 1) * 68 + c0]     = acc10;
    G_lds[(2 * p + 1) * 68 + c0 + 1] = acc11;
    __syncthreads();
    const int j  = t & 63;
    const int iw = t >> 6;
#pragma unroll
    for (int rr = 0; rr < 4; ++rr) {
        const int i = iw * 4 + rr;
        float z = wiu[(size_t)(r0 + i) * 64 + j];
#pragma unroll
        for (int m = 0; m < 64; ++m)
            z = fmaf(G_lds[i * 68 + m], W_lds[j * 65 + m], z);
        const float hv = tanhf(z);
        h_out[(size_t)(r0 + i) * 64 + j] = hv;
        if (out2) out2[(size_t)(r0 + i) * 128 + out_col0 + j] = hv;
    }
}

// ---------------------------------------------------------------------------
extern "C" void kernel_launch(void* const* d_in, const int* in_sizes, int n_in,
                              void* d_out, int out_size, void* d_ws, size_t ws_size,
                              hipStream_t stream) {
    const float* X    = (const float*)d_in[0];
    const float* L    = (const float*)d_in[1];
    const float* Wih0 = (const float*)d_in[2];
    const float* Whh0 = (const float*)d_in[3];
    const float* Wih1 = (const float*)d_in[4];
    const float* Whh1 = (const float*)d_in[5];
    float* out = (float*)d_out;
    char* ws = (char*)d_ws;

    const size_t MB = 1024 * 1024;
    const size_t need = 77 * MB;

    if (ws_size >= need) {
        short* Ahi = (short*)(ws);                 // 32 MB
        short* Alo = (short*)(ws + 32 * MB);       // 32 MB
        short* Bhi = (short*)(ws + 64 * MB);       // 0.5 MB
        short* Blo = (short*)(ws + 64 * MB + 512 * 1024);
        float* wiu = (float*)(ws + 65 * MB);       // 1 MB
        float* hA  = (float*)(ws + 66 * MB);       // 1 MB
        float* hB  = (float*)(ws + 67 * MB);       // 1 MB
        float* Gp  = (float*)(ws + 68 * MB);       // 8 MB
        unsigned char* bar = (unsigned char*)(ws + 76 * MB);

        hipMemsetAsync(bar, 0, 1024, stream);      // barrier cnt+gen = 0
        convert_L<<<8192, 256, 0, stream>>>(L, Ahi, Alo);
        gesn_persistent<<<NBLK, TPB, 0, stream>>>(
            Ahi, Alo, Bhi, Blo, X, Wih0, Whh0, Wih1, Whh1,
            wiu, hA, hB, Gp, out,
            (unsigned*)bar, (unsigned*)(bar + 256));
    } else {
        // f32 fallback (verified round-0 path)
        float* wiu = (float*)(ws);
        float* hA  = (float*)(ws + (1u << 20));
        float* hB  = (float*)(ws + (2u << 20));
        for (int layer = 0; layer < 2; ++layer) {
            const float* x   = layer ? hB : X;
            const float* Wih = layer ? Wih1 : Wih0;
            const float* Whh = layer ? Whh1 : Whh0;
            gesn_input_kernel<<<1024, 256, 0, stream>>>(x, Wih, wiu, hA);
            float* cur = hA;
            float* nxt = hB;
            for (int it = 0; it < 9; ++it) {
                float* o2 = (it == 8) ? out : nullptr;
                gesn_iter_kernel<<<256, 256, 0, stream>>>(L, cur, wiu, Whh, nxt,
                                                          o2, layer * 64);
                float* tmp = cur; cur = nxt; nxt = tmp;
            }
        }
    }
}

// Round 8
// 561.422 us; speedup vs baseline: 2.6103x; 2.6103x over previous
//
#include <hip/hip_runtime.h>
#include <hip/hip_bf16.h>
#include <math.h>

// DeepGESN: 2 layers of h = tanh(wiu + L @ (h @ W_hh^T)), 10 iters each.
// Rewrite: L@(h@W) == (L@h)@W. G=L@h in bf16 MFMA with two-term split
// (L=Lhi+Llo, h=hhi+hlo, 3 products; measured absmax 0.0093 vs 0.02 thr).
//
// R8: FUSED iteration kernel (mm + reduce + projection + tanh + pack in one
// dispatch). Block = 16 rows x full K (grid 256 = 1 block/CU); wave w owns
// K-chunk [w*16, w*16+16) kb -- same 8-way K-grouping as the old grid-level
// K-split, so summation order (and absmax) is IDENTICAL. Partials reduced
// through LDS; epilogue fused. Gp eliminated (-16MB/iter L3 round-trip),
// 39 dispatches -> 21, no staging barriers in the MFMA loop (B read direct
// from L2-resident 1MB pack). B-pack double-buffered across iterations
// (read cur / write nxt) to avoid cross-block races.
// R7 lesson (counters): A-in-VGPR spills (VGPR capped 128, WRITE_SIZE
// bloat); so A is STREAMED per-kbl and nothing big is kept live.
//
// Pack layouts (lane-linear dwordx4 fragment loads):
//  Apack[rb][kb][l][8]: val = L[rb*16 + (l&15)][kb*32 + 8*(l>>4) + j]
//  Bpack[kb][cf][l][8]: val = h[kb*32 + 8*(l>>4) + j][cf*16 + (l&15)]
// mfma_f32_16x16x32_bf16: D[(l>>4)*4+r][l&15] (m89/m91 layout).

#define NN 4096
#define HH 64

typedef float  f32x4  __attribute__((ext_vector_type(4)));
typedef short  bf16x8 __attribute__((ext_vector_type(8)));

static __device__ __forceinline__ unsigned short bf16_bits(__hip_bfloat16 b) {
    union { __hip_bfloat16 b; unsigned short u; } cv; cv.b = b; return cv.u;
}

// ---------------------------------------------------------------------------
// Split + pack L -> Ahi/Alo (bf16 fragment-linear, 32MB each)
// grid 8192: rb = bid>>5 (256), kg = bid&31 (128-k group)
// ---------------------------------------------------------------------------
__global__ __launch_bounds__(256) void convert_L(
    const float* __restrict__ L, short* __restrict__ Ahi, short* __restrict__ Alo)
{
    __shared__ float T[16 * 132];
    const int t  = threadIdx.x;
    const int rb = blockIdx.x >> 5;
    const int kg = blockIdx.x & 31;

    {
        const int row = t >> 4;
        const int c4  = (t & 15) * 4;
        const float* src = L + (size_t)(rb * 16 + row) * NN + kg * 128;
        float4 v0 = *reinterpret_cast<const float4*>(src + c4);
        float4 v1 = *reinterpret_cast<const float4*>(src + c4 + 64);
        *reinterpret_cast<float4*>(&T[row * 132 + c4])      = v0;
        *reinterpret_cast<float4*>(&T[row * 132 + c4 + 64]) = v1;
    }
    __syncthreads();

    const int kbl = t >> 6;
    const int l   = t & 63;
    const int r   = l & 15, g = l >> 4;
    short hi8[8], lo8[8];
#pragma unroll
    for (int j = 0; j < 8; ++j) {
        const float v = T[r * 132 + kbl * 32 + g * 8 + j];
        __hip_bfloat16 bh = __float2bfloat16(v);
        const float vh = __bfloat162float(bh);
        __hip_bfloat16 bl = __float2bfloat16(v - vh);
        hi8[j] = (short)bf16_bits(bh);
        lo8[j] = (short)bf16_bits(bl);
    }
    const size_t off = ((size_t)(rb * 128 + kg * 4 + kbl) * 64 + l) * 8;
    *reinterpret_cast<bf16x8*>(Ahi + off) = *reinterpret_cast<bf16x8*>(hi8);
    *reinterpret_cast<bf16x8*>(Alo + off) = *reinterpret_cast<bf16x8*>(lo8);
}

// ---------------------------------------------------------------------------
// Fused iteration: h_out = tanh(wiu + (L@h)@W^T), B-pack of h_out.
// grid 256 x 512thr. Block b: rows r0=b*16 (rb = b). Wave w: kb chunk
// [w*16, (w+1)*16). A,B streamed from global (L3/L2). Wave partials
// reduced in LDS, then projection epilogue + tanh + pack.
// ---------------------------------------------------------------------------
__global__ __launch_bounds__(512) void gesn_iter_fused(
    const short* __restrict__ Ahi,  const short* __restrict__ Alo,
    const short* __restrict__ BhiIn, const short* __restrict__ BloIn,
    short* __restrict__ BhiOut, short* __restrict__ BloOut,
    const float* __restrict__ wiu,  const float* __restrict__ W,
    float* __restrict__ hf32,
    float* __restrict__ out2, int outc0)
{
    __shared__ float W_lds[64 * 65];            // 16640 B
    __shared__ float Gpart[8][16 * 68];         // 34816 B  wave partials
    __shared__ float Gred[16 * 68];             //  4352 B  reduced G
    __shared__ unsigned short Hi_lds[16 * 66];  //  2112 B
    __shared__ unsigned short Lo_lds[16 * 66];  //  2112 B

    const int t  = threadIdx.x;
    const int w  = t >> 6, l = t & 63;
    const int b  = blockIdx.x;
    const int rb = b;                  // 16-row block index
    const int r0 = b * 16;
    const int kb0 = w * 16;            // wave's K-chunk start (kb units)

    {   // W load: 512 thr x 8 elems (needed only at epilogue; barriers cover)
        const int j  = t >> 3;
        const int k0 = (t & 7) * 8;
#pragma unroll
        for (int q = 0; q < 8; ++q)
            W_lds[j * 65 + k0 + q] = W[j * 64 + k0 + q];
    }

    // ---- MFMA main loop: acc = sum over wave's 16 kb of (L@h) products ----
    const size_t abase = ((size_t)(rb * 128 + kb0) * 64 + l) * 8;
    f32x4 accP[4] = {};                // aH*bH
    f32x4 accQ[4] = {};                // aH*bL + aL*bH

#pragma unroll
    for (int kbl = 0; kbl < 16; ++kbl) {
        const bf16x8 a_hi = *reinterpret_cast<const bf16x8*>(
            Ahi + abase + (size_t)kbl * 512);
        const bf16x8 a_lo = *reinterpret_cast<const bf16x8*>(
            Alo + abase + (size_t)kbl * 512);
        bf16x8 bH[4], bL[4];
#pragma unroll
        for (int cf = 0; cf < 4; ++cf) {
            const size_t bo = ((size_t)((kb0 + kbl) * 4 + cf) * 64 + l) * 8;
            bH[cf] = *reinterpret_cast<const bf16x8*>(BhiIn + bo);
            bL[cf] = *reinterpret_cast<const bf16x8*>(BloIn + bo);
        }
#pragma unroll
        for (int cf = 0; cf < 4; ++cf) {
            accP[cf] = __builtin_amdgcn_mfma_f32_16x16x32_bf16(
                a_hi, bH[cf], accP[cf], 0, 0, 0);
            accQ[cf] = __builtin_amdgcn_mfma_f32_16x16x32_bf16(
                a_hi, bL[cf], accQ[cf], 0, 0, 0);
            accQ[cf] = __builtin_amdgcn_mfma_f32_16x16x32_bf16(
                a_lo, bH[cf], accQ[cf], 0, 0, 0);
        }
    }

    // ---- wave partials -> LDS (D-layout: row=(l>>4)*4+r, col=cf*16+(l&15))
    {
        const int col0   = l & 15;
        const int rbase4 = (l >> 4) * 4;
#pragma unroll
        for (int cf = 0; cf < 4; ++cf)
#pragma unroll
            for (int r = 0; r < 4; ++r)
                Gpart[w][(rbase4 + r) * 68 + cf * 16 + col0]
                    = accP[cf][r] + accQ[cf][r];
    }
    __syncthreads();

    // ---- reduce 8 wave partials (w ascending = old K-split order) ----
    {   // 1024 slots, thread t reduces slots 2t, 2t+1 (float2)
        const int idx = t * 2;
        const int i   = idx >> 6;
        const int m   = idx & 63;
        float2 sum = *reinterpret_cast<const float2*>(&Gpart[0][i * 68 + m]);
#pragma unroll
        for (int ww = 1; ww < 8; ++ww) {
            const float2 v = *reinterpret_cast<const float2*>(&Gpart[ww][i * 68 + m]);
            sum.x += v.x; sum.y += v.y;
        }
        *reinterpret_cast<float2*>(&Gred[i * 68 + m]) = sum;
    }
    __syncthreads();

    // ---- epilogue: z = wiu + Gred @ W^T ; h = tanh(z) ----
    const int j  = t & 63;
    const int ig = t >> 6;             // 0..7 (wave-uniform)
#pragma unroll
    for (int rr = 0; rr < 2; ++rr) {
        const int i = ig * 2 + rr;     // 0..15
        float z = wiu[(size_t)(r0 + i) * HH + j];
#pragma unroll
        for (int m = 0; m < 64; ++m)
            z = fmaf(Gred[i * 68 + m], W_lds[j * 65 + m], z);
        const float hv = tanhf(z);
        hf32[(size_t)(r0 + i) * HH + j] = hv;
        if (out2) out2[(size_t)(r0 + i) * 128 + outc0 + j] = hv;
        __hip_bfloat16 bh = __float2bfloat16(hv);
        const float vh = __bfloat162float(bh);
        __hip_bfloat16 bl = __float2bfloat16(hv - vh);
        Hi_lds[i * 66 + j] = bf16_bits(bh);
        Lo_lds[i * 66 + j] = bf16_bits(bl);
    }
    __syncthreads();

    // ---- pack h_out into NEXT iteration's B buffers ----
    if (t < 128) {
        const int j2     = t & 63;
        const int glocal = t >> 6;                     // 0..1
        const int kb     = r0 >> 5;
        const int gg     = ((r0 & 31) >> 3) + glocal;  // 8-row group in kb
        const int cf     = j2 >> 4;
        const int lane   = gg * 16 + (j2 & 15);
        short hi8[8], lo8[8];
#pragma unroll
        for (int jj = 0; jj < 8; ++jj) {
            const int i = glocal * 8 + jj;
            hi8[jj] = (short)Hi_lds[i * 66 + j2];
            lo8[jj] = (short)Lo_lds[i * 66 + j2];
        }
        const size_t off = ((size_t)(kb * 4 + cf) * 64 + lane) * 8;
        *reinterpret_cast<bf16x8*>(BhiOut + off) = *reinterpret_cast<bf16x8*>(hi8);
        *reinterpret_cast<bf16x8*>(BloOut + off) = *reinterpret_cast<bf16x8*>(lo8);
    }
}

// ---------------------------------------------------------------------------
// Input kernel (iter 1): wiu = x@Wih^T; h = tanh(wiu); B-pack of h.
// grid 256 x 256thr, 16 rows/block. (R6's verified gesn_post, nsplit==0.)
// ---------------------------------------------------------------------------
__global__ __launch_bounds__(256) void gesn_input_pack(
    const float* __restrict__ x, float* __restrict__ wiu_out,
    const float* __restrict__ W, float* __restrict__ hf32,
    short* __restrict__ Bhi, short* __restrict__ Blo)
{
    __shared__ float W_lds[64 * 65];
    __shared__ float G_lds[16 * 68];
    __shared__ unsigned short Hi_lds[16 * 66];
    __shared__ unsigned short Lo_lds[16 * 66];
    const int t = threadIdx.x;

    {   // W load
        const int j  = t >> 2;
        const int k0 = (t & 3) << 4;
#pragma unroll
        for (int q = 0; q < 16; ++q)
            W_lds[j * 65 + k0 + q] = W[j * 64 + k0 + q];
    }
    const int r0 = blockIdx.x * 16;

    {   // x rows -> LDS: 16x64 f32 = 256 float4
        const int row = t >> 4;
        const int c4  = (t & 15) * 4;
        *reinterpret_cast<float4*>(&G_lds[row * 68 + c4]) =
            *reinterpret_cast<const float4*>(x + (size_t)(r0 + row) * HH + c4);
    }
    __syncthreads();

    const int j  = t & 63;
    const int ig = t >> 6;
#pragma unroll
    for (int rr = 0; rr < 4; ++rr) {
        const int i = ig * 4 + rr;            // 0..15
        float z = 0.f;
#pragma unroll
        for (int m = 0; m < 64; ++m)
            z = fmaf(G_lds[i * 68 + m], W_lds[j * 65 + m], z);
        wiu_out[(size_t)(r0 + i) * HH + j] = z;
        const float hv = tanhf(z);
        hf32[(size_t)(r0 + i) * HH + j] = hv;
        __hip_bfloat16 bh = __float2bfloat16(hv);
        const float vh = __bfloat162float(bh);
        __hip_bfloat16 bl = __float2bfloat16(hv - vh);
        Hi_lds[i * 66 + j] = bf16_bits(bh);
        Lo_lds[i * 66 + j] = bf16_bits(bl);
    }
    __syncthreads();

    if (t < 128) {
        const int j2     = t & 63;
        const int glocal = t >> 6;
        const int kb     = r0 >> 5;
        const int gg     = ((r0 & 31) >> 3) + glocal;
        const int cf     = j2 >> 4;
        const int lane   = gg * 16 + (j2 & 15);
        short hi8[8], lo8[8];
#pragma unroll
        for (int jj = 0; jj < 8; ++jj) {
            const int i = glocal * 8 + jj;
            hi8[jj] = (short)Hi_lds[i * 66 + j2];
            lo8[jj] = (short)Lo_lds[i * 66 + j2];
        }
        const size_t off = ((size_t)(kb * 4 + cf) * 64 + lane) * 8;
        *reinterpret_cast<bf16x8*>(Bhi + off) = *reinterpret_cast<bf16x8*>(hi8);
        *reinterpret_cast<bf16x8*>(Blo + off) = *reinterpret_cast<bf16x8*>(lo8);
    }
}

// ---------------------------------------------------------------------------
// Fallback f32 path (round-0 kernels, small-ws safety)
// ---------------------------------------------------------------------------
__global__ __launch_bounds__(256) void gesn_input_kernel(
    const float* __restrict__ x, const float* __restrict__ W,
    float* __restrict__ wiu, float* __restrict__ h)
{
    __shared__ float W_lds[64 * 65];
    __shared__ float x_lds[256];
    const int t = threadIdx.x;
    {
        const int j  = t >> 2;
        const int k0 = (t & 3) << 4;
#pragma unroll
        for (int q = 0; q < 16; ++q)
            W_lds[j * 65 + k0 + q] = W[j * 64 + k0 + q];
    }
    const int i0 = blockIdx.x * 4;
    x_lds[t] = x[i0 * 64 + t];
    __syncthreads();
    const int j = t & 63, i = t >> 6;
    float z = 0.f;
#pragma unroll
    for (int k = 0; k < 64; ++k)
        z = fmaf(x_lds[i * 64 + k], W_lds[j * 65 + k], z);
    const int gidx = (i0 + i) * 64 + j;
    wiu[gidx] = z;
    h[gidx]   = tanhf(z);
}

__global__ __launch_bounds__(256) void gesn_iter_kernel(
    const float* __restrict__ L, const float* __restrict__ h_in,
    const float* __restrict__ wiu, const float* __restrict__ W,
    float* __restrict__ h_out, float* __restrict__ out2, int out_col0)
{
    __shared__ float h_lds[64 * 64];
    __shared__ float L_lds[16 * 68];
    __shared__ float G_lds[16 * 68];
    __shared__ float W_lds[64 * 65];
    const int t = threadIdx.x;
    {
        const int j  = t >> 2;
        const int k0 = (t & 3) << 4;
#pragma unroll
        for (int q = 0; q < 16; ++q)
            W_lds[j * 65 + k0 + q] = W[j * 64 + k0 + q];
    }
    const int r0 = blockIdx.x * 16;
    const int p  = t >> 5;
    const int c0 = (t & 31) * 2;
    float acc00 = 0.f, acc01 = 0.f, acc10 = 0.f, acc11 = 0.f;
    const int lr = t >> 4;
    const int lc = (t & 15) * 4;
    for (int kb = 0; kb < 64; ++kb) {
        __syncthreads();
        const float4 lv = *reinterpret_cast<const float4*>(
            &L[(size_t)(r0 + lr) * 4096 + kb * 64 + lc]);
        *reinterpret_cast<float4*>(&L_lds[lr * 68 + lc]) = lv;
        const float4* hsrc = reinterpret_cast<const float4*>(h_in + kb * 4096);
        float4* hdst = reinterpret_cast<float4*>(h_lds);
#pragma unroll
        for (int q = 0; q < 4; ++q)
            hdst[t + 256 * q] = hsrc[t + 256 * q];
        __syncthreads();
#pragma unroll
        for (int kk = 0; kk < 64; ++kk) {
            const float  lv0 = L_lds[(2 * p) * 68 + kk];
            const float  lv1 = L_lds[(2 * p + 1) * 68 + kk];
            const float2 hv  = *reinterpret_cast<const float2*>(&h_lds[kk * 64 + c0]);
            acc00 = fmaf(lv0, hv.x, acc00);
            acc01 = fmaf(lv0, hv.y, acc01);
            acc10 = fmaf(lv1, hv.x, acc10);
            acc11 = fmaf(lv1, hv.y, acc11);
        }
    }
    G_lds[(2 * p) * 68 + c0]         = acc00;
    G_lds[(2 * p) * 68 + c0 + 1]     = acc01;
    G_lds[(2 * p + 1) * 68 + c0]     = acc10;
    G_lds[(2 * p + 1) * 68 + c0 + 1] = acc11;
    __syncthreads();
    const int j  = t & 63;
    const int iw = t >> 6;
#pragma unroll
    for (int rr = 0; rr < 4; ++rr) {
        const int i = iw * 4 + rr;
        float z = wiu[(size_t)(r0 + i) * 64 + j];
#pragma unroll
        for (int m = 0; m < 64; ++m)
            z = fmaf(G_lds[i * 68 + m], W_lds[j * 65 + m], z);
        const float hv = tanhf(z);
        h_out[(size_t)(r0 + i) * 64 + j] = hv;
        if (out2) out2[(size_t)(r0 + i) * 128 + out_col0 + j] = hv;
    }
}

// ---------------------------------------------------------------------------
extern "C" void kernel_launch(void* const* d_in, const int* in_sizes, int n_in,
                              void* d_out, int out_size, void* d_ws, size_t ws_size,
                              hipStream_t stream) {
    const float* X    = (const float*)d_in[0];
    const float* L    = (const float*)d_in[1];
    const float* Wih0 = (const float*)d_in[2];
    const float* Whh0 = (const float*)d_in[3];
    const float* Wih1 = (const float*)d_in[4];
    const float* Whh1 = (const float*)d_in[5];
    float* out = (float*)d_out;
    char* ws = (char*)d_ws;

    const size_t MB = 1024 * 1024;
    const size_t need = 72 * MB;

    if (ws_size >= need) {
        short* Ahi  = (short*)(ws);                          // 32 MB
        short* Alo  = (short*)(ws + 32 * MB);                // 32 MB
        short* BhiA = (short*)(ws + 64 * MB);                // 0.5 MB
        short* BloA = (short*)(ws + 64 * MB + 512 * 1024);   // 0.5 MB
        short* BhiB = (short*)(ws + 65 * MB);                // 0.5 MB
        short* BloB = (short*)(ws + 65 * MB + 512 * 1024);   // 0.5 MB
        float* wiu  = (float*)(ws + 66 * MB);                // 1 MB
        float* hA   = (float*)(ws + 67 * MB);                // 1 MB
        float* hB   = (float*)(ws + 68 * MB);                // 1 MB

        convert_L<<<8192, 256, 0, stream>>>(L, Ahi, Alo);

        for (int layer = 0; layer < 2; ++layer) {
            const float* x   = layer ? hA : X;   // layer1 input = layer0 final h
            const float* Wih = layer ? Wih1 : Wih0;
            const float* Whh = layer ? Whh1 : Whh0;
            float* hcur      = layer ? hB : hA;

            // iter 1: wiu = x@Wih^T; h = tanh(wiu); pack into buffer A
            gesn_input_pack<<<256, 256, 0, stream>>>(x, wiu, Wih, hcur,
                                                     BhiA, BloA);
            // iters 2..10: fused, B double-buffered A<->B
            short *bi_h = BhiA, *bi_l = BloA, *bo_h = BhiB, *bo_l = BloB;
            for (int it = 0; it < 9; ++it) {
                float* o2 = (it == 8) ? out : nullptr;
                gesn_iter_fused<<<256, 512, 0, stream>>>(
                    Ahi, Alo, bi_h, bi_l, bo_h, bo_l,
                    wiu, Whh, hcur, o2, layer * 64);
                short* th = bi_h; bi_h = bo_h; bo_h = th;
                short* tl = bi_l; bi_l = bo_l; bo_l = tl;
            }
        }
    } else {
        // f32 fallback (verified round-0 path)
        float* wiu = (float*)(ws);
        float* hA  = (float*)(ws + (1u << 20));
        float* hB  = (float*)(ws + (2u << 20));
        for (int layer = 0; layer < 2; ++layer) {
            const float* x   = layer ? hB : X;
            const float* Wih = layer ? Wih1 : Wih0;
            const float* Whh = layer ? Whh1 : Whh0;
            gesn_input_kernel<<<1024, 256, 0, stream>>>(x, Wih, wiu, hA);
            float* cur = hA;
            float* nxt = hB;
            for (int it = 0; it < 9; ++it) {
                float* o2 = (it == 8) ? out : nullptr;
                gesn_iter_kernel<<<256, 256, 0, stream>>>(L, cur, wiu, Whh, nxt,
                                                          o2, layer * 64);
                float* tmp = cur; cur = nxt; nxt = tmp;
            }
        }
    }
}